// Round 4
// baseline (968.541 us; speedup 1.0000x reference)
//
#include <hip/hip_runtime.h>
#include <math.h>

#define Bc 4
#define Lc 4096
#define Dc 1024
#define Mtot (Bc*Lc)          // 16384 flattened tokens
#define NSEG 64
#define SEGLEN (Lc/NSEG)      // 64
#define MAXFIX 128            // repair capacity (expected ~13 flagged tokens)

typedef __attribute__((ext_vector_type(8))) short short8;
typedef __attribute__((ext_vector_type(4))) float floatx4;
typedef unsigned short us;

// ---- workspace layout (bytes) — total ~10.5 MB ----
#define OFF_QHI    ((size_t)0)                       // 1024*1024 bf16 each
#define OFF_QLO    ((size_t)2097152)
#define OFF_KHI    ((size_t)4194304)
#define OFF_KLO    ((size_t)6291456)
#define OFF_PARTS  ((size_t)8388608)                 // 3*Mtot f32 (dot,qn,kn)
#define OFF_FLAGS  (OFF_PARTS + (size_t)196608)      // int count + MAXFIX idx (pad 1024)
#define OFF_RPART  (OFF_FLAGS + (size_t)1024)        // 3*MAXFIX f32 (pad 2048)
#define OFF_COSV   (OFF_RPART + (size_t)2048)        // Mtot f32
#define OFF_ASEG   (OFF_COSV + (size_t)65536)
#define OFF_BSEG   (OFF_ASEG + (size_t)1024)
#define OFF_CARRY  (OFF_BSEG + (size_t)1048576)

// ---------------------------------------------------------------------------
// bf16 split helpers (RNE)
// ---------------------------------------------------------------------------
__device__ inline us f2bf(float x) {
    unsigned int u = __float_as_uint(x);
    u += 0x7FFFu + ((u >> 16) & 1u);
    return (us)(u >> 16);
}
__device__ inline float bf2f(us h) {
    return __uint_as_float(((unsigned int)h) << 16);
}

// zero parts[3*Mtot] + flags[0] + rparts[3*MAXFIX]
__global__ __launch_bounds__(256)
void zero_kernel(float* __restrict__ parts, int* __restrict__ flags,
                 float* __restrict__ rparts)
{
    const int idx = blockIdx.x*256 + threadIdx.x;
    if (idx < 3*Mtot) parts[idx] = 0.f;
    if (idx < 3*MAXFIX) rparts[idx] = 0.f;
    if (idx == 0) flags[0] = 0;
}

__global__ __launch_bounds__(256)
void convert_w_kernel(const float* __restrict__ W,
                      us* __restrict__ Whi,
                      us* __restrict__ Wlo)
{
    const int e4 = blockIdx.x*256 + threadIdx.x;   // over 1024*256 float4s
    const float4 v = *(const float4*)&W[(size_t)e4*4];
    ushort4 h, l;
    h.x = f2bf(v.x); l.x = f2bf(v.x - bf2f(h.x));
    h.y = f2bf(v.y); l.y = f2bf(v.y - bf2f(h.y));
    h.z = f2bf(v.z); l.z = f2bf(v.z - bf2f(h.z));
    h.w = f2bf(v.w); l.w = f2bf(v.w - bf2f(h.w));
    *(ushort4*)&Whi[(size_t)e4*4] = h;
    *(ushort4*)&Wlo[(size_t)e4*4] = l;
}

// ---------------------------------------------------------------------------
// Fused MFMA GEMM, in-kernel X->bf16 hi/lo split, 3-product emulation.
// LDS layout is 16B-granule swizzled: granule slot = (koblk + row/2) & 3
// -> 8 consecutive fragment rows hit 8 distinct bank quads (conflict-free).
// XCD-grouped block mapping: all 8 bn-blocks of a bm on one XCD's L2.
// ---------------------------------------------------------------------------
#define AS1C const __attribute__((address_space(1))) void*
#define AS3P __attribute__((address_space(3))) void*

__global__ __launch_bounds__(256, 3)
void gemm_cos_kernel(const float* __restrict__ X,
                     const us* __restrict__ Qhi,
                     const us* __restrict__ Qlo,
                     const us* __restrict__ Khi,
                     const us* __restrict__ Klo,
                     float* __restrict__ parts)
{
    __shared__ __align__(16) us lds[24640];        // 49,280 B
    us* AsH = lds;                                  // 129 x 32 (swizzled granules)
    us* AsL = lds + 4128;
    us* Bs  = lds + 8256;                           // 4 x (128 x 32): qH,qL,kH,kL

    const int tid  = threadIdx.x;
    const int lane = tid & 63;
    const int wv   = tid >> 6;
    const int wm   = wv >> 1;
    const int wn   = wv & 1;
    // XCD-aware mapping: xcd = blk&7 (round-robin); 8 bn-blocks of a bm adjacent
    const int blk  = blockIdx.x;
    const int jj   = blk >> 3;
    const int bm   = (blk & 7)*16 + (jj >> 3);
    const int bn   = jj & 7;
    const int t0   = bm * 128;
    const int nb   = bn * 128;

    floatx4 accq[4][4], acck[4][4];
    const floatx4 zz = {0.f, 0.f, 0.f, 0.f};
    #pragma unroll
    for (int i = 0; i < 4; i++)
        #pragma unroll
        for (int j = 0; j < 4; j++) { accq[i][j] = zz; acck[i][j] = zz; }

    const us* Wt[4] = {Qhi, Qlo, Khi, Klo};

    const int lrow  = lane & 15;
    const int koblk = lane >> 4;         // 0..3 (16B granule within 64B row)

    for (int ch = 0; ch < 32; ++ch) {
        const int k0 = ch << 5;

        // ---- stage A: fp32 X tile 129x32 -> hi/lo bf16, swizzled ds_write ----
        for (int g = tid; g < 1032; g += 256) {
            const int row = g >> 3, c4 = g & 7;          // c4: half-granule (8B)
            int t = t0 + row; if (t >= Mtot) t = Mtot - 1;
            const float4 v = *(const float4*)&X[(size_t)t*Dc + k0 + c4*4];
            ushort4 h, l;
            h.x = f2bf(v.x); l.x = f2bf(v.x - bf2f(h.x));
            h.y = f2bf(v.y); l.y = f2bf(v.y - bf2f(h.y));
            h.z = f2bf(v.z); l.z = f2bf(v.z - bf2f(h.z));
            h.w = f2bf(v.w); l.w = f2bf(v.w - bf2f(h.w));
            const int slot = ((c4 >> 1) + (row >> 1)) & 3;
            const int off  = row*32 + slot*8 + (c4 & 1)*4;
            *(ushort4*)&AsH[off] = h;
            *(ushort4*)&AsL[off] = l;
        }
        // ---- stage B: 4 weight tiles via global_load_lds, swizzled granules ----
        #pragma unroll
        for (int it = 0; it < 8; ++it) {
            const int gb   = it*256 + wv*64;             // wave-uniform granule base
            const int g    = gb + lane;
            const int tile = g >> 9;                     // wave-uniform (64-runs don't cross)
            const int gg   = g & 511;
            const int row  = gg >> 2, slot = gg & 3;
            const int kb   = (slot - (row >> 1)) & 3;    // inverse swizzle
            const us* gp = Wt[tile] + (size_t)(nb + row)*Dc + k0 + kb*8;
            __builtin_amdgcn_global_load_lds((AS1C)gp, (AS3P)(Bs + gb*8), 16, 0, 0);
        }
        __syncthreads();

        short8 aq[4], ak[4];
        // hi-A fragments (reused across W-hi and W-lo phases)
        #pragma unroll
        for (int i = 0; i < 4; ++i) {
            const int r = wm*64 + i*16 + lrow;
            aq[i] = *(const short8*)&AsH[r*32 + (((koblk + (r>>1)) & 3) << 3)];
            ak[i] = *(const short8*)&AsH[(r+1)*32 + (((koblk + ((r+1)>>1)) & 3) << 3)];
        }
        #pragma unroll
        for (int pb = 0; pb < 2; ++pb) {                 // pb=0: W-hi, pb=1: W-lo
            const us* bq = Bs + (pb ? 4096 : 0);
            const us* bk = Bs + (pb ? 12288 : 8192);
            #pragma unroll
            for (int j = 0; j < 4; ++j) {
                const int rb = wn*64 + j*16 + lrow;
                const int boff = rb*32 + (((koblk + (rb>>1)) & 3) << 3);
                const short8 fbq = *(const short8*)&bq[boff];
                const short8 fbk = *(const short8*)&bk[boff];
                #pragma unroll
                for (int i = 0; i < 4; ++i) {
                    accq[i][j] = __builtin_amdgcn_mfma_f32_16x16x32_bf16(aq[i], fbq, accq[i][j], 0, 0, 0);
                    acck[i][j] = __builtin_amdgcn_mfma_f32_16x16x32_bf16(ak[i], fbk, acck[i][j], 0, 0, 0);
                }
            }
        }
        // lo-A fragments x W-hi
        #pragma unroll
        for (int i = 0; i < 4; ++i) {
            const int r = wm*64 + i*16 + lrow;
            aq[i] = *(const short8*)&AsL[r*32 + (((koblk + (r>>1)) & 3) << 3)];
            ak[i] = *(const short8*)&AsL[(r+1)*32 + (((koblk + ((r+1)>>1)) & 3) << 3)];
        }
        #pragma unroll
        for (int j = 0; j < 4; ++j) {
            const int rb = wn*64 + j*16 + lrow;
            const int boff = rb*32 + (((koblk + (rb>>1)) & 3) << 3);
            const short8 fbq = *(const short8*)&Bs[boff];          // qH
            const short8 fbk = *(const short8*)&Bs[8192 + boff];   // kH
            #pragma unroll
            for (int i = 0; i < 4; ++i) {
                accq[i][j] = __builtin_amdgcn_mfma_f32_16x16x32_bf16(aq[i], fbq, accq[i][j], 0, 0, 0);
                acck[i][j] = __builtin_amdgcn_mfma_f32_16x16x32_bf16(ak[i], fbk, acck[i][j], 0, 0, 0);
            }
        }
        __syncthreads();
    }

    // ---- epilogue: per-row dot/qn/kn over this WG's 128 cols, then atomics ----
    #pragma unroll
    for (int i = 0; i < 4; ++i) {
        #pragma unroll
        for (int reg = 0; reg < 4; ++reg) {
            float d = 0.f, qq = 0.f, kk = 0.f;
            #pragma unroll
            for (int j = 0; j < 4; ++j) {
                const float qv = accq[i][j][reg];
                const float kv = acck[i][j][reg];
                d  += qv * kv;
                qq += qv * qv;
                kk += kv * kv;
            }
            #pragma unroll
            for (int m = 1; m <= 8; m <<= 1) {
                d  += __shfl_xor(d,  m);
                qq += __shfl_xor(qq, m);
                kk += __shfl_xor(kk, m);
            }
            if ((lane & 15) == 0) {
                const int row = t0 + wm*64 + i*16 + ((lane >> 4) << 2) + reg;
                atomicAdd(&parts[row],          d);
                atomicAdd(&parts[Mtot + row],   qq);
                atomicAdd(&parts[2*Mtot + row], kk);
            }
        }
    }
}

// ---------------------------------------------------------------------------
// finalize cos + flag near-boundary tokens (|cos| < 3e-5) for exact repair
// ---------------------------------------------------------------------------
__global__ __launch_bounds__(256)
void cos_fin_kernel(const float* __restrict__ parts,
                    float* __restrict__ cosv,
                    int* __restrict__ flags)
{
    const int t = blockIdx.x*256 + threadIdx.x;
    if (t >= Mtot) return;
    const float dot = parts[t];
    const float qn  = parts[Mtot + t];
    const float kn  = parts[2*Mtot + t];
    const float c = dot / (fmaxf(sqrtf(qn), 1e-12f) * fmaxf(sqrtf(kn), 1e-12f));
    cosv[t] = c;
    if (fabsf(c) < 3e-5f && (t & (Lc-1)) != (Lc-1)) {
        const int idx = atomicAdd(flags, 1);
        if (idx < MAXFIX) flags[1 + idx] = t;
    }
}

// ---------------------------------------------------------------------------
// repair, pass 1: rows striped across 256 blocks (wave w owns row blk*4+w).
// Each wave computes exact fp32 q_n, k_n for its row and all flagged tokens;
// partial (q*k, q^2, k^2) atomically added into rparts[3][MAXFIX].
// Weights are read ONCE across the grid (vs per-token in round 3).
// ---------------------------------------------------------------------------
__global__ __launch_bounds__(256)
void repair_partial_kernel(const float* __restrict__ X,
                           const float* __restrict__ Qw,
                           const float* __restrict__ Kw,
                           const int* __restrict__ flags,
                           float* __restrict__ rparts)
{
    __shared__ __align__(16) float x0[Dc];
    __shared__ __align__(16) float x1[Dc];
    const int tid  = threadIdx.x;
    const int lane = tid & 63;
    const int w    = tid >> 6;
    const int n    = blockIdx.x*4 + w;          // weight row owned by this wave
    const int count = min(flags[0], MAXFIX);
    const float* qrow = Qw + (size_t)n*Dc;
    const float* krow = Kw + (size_t)n*Dc;
    for (int fi = 0; fi < count; ++fi) {
        const int t = flags[1 + fi];
        *(float4*)&x0[tid*4] = *(const float4*)&X[(size_t)t*Dc + tid*4];
        *(float4*)&x1[tid*4] = *(const float4*)&X[(size_t)(t+1)*Dc + tid*4];
        __syncthreads();
        float sq = 0.f, sk = 0.f;
        #pragma unroll
        for (int c = 0; c < 4; ++c) {
            const int k4 = lane + c*64;
            const float4 qv = *(const float4*)&qrow[k4*4];
            const float4 kv = *(const float4*)&krow[k4*4];
            const float4 a0 = *(const float4*)&x0[k4*4];
            const float4 a1 = *(const float4*)&x1[k4*4];
            sq += qv.x*a0.x + qv.y*a0.y + qv.z*a0.z + qv.w*a0.w;
            sk += kv.x*a1.x + kv.y*a1.y + kv.z*a1.z + kv.w*a1.w;
        }
        #pragma unroll
        for (int m = 1; m < 64; m <<= 1) {
            sq += __shfl_xor(sq, m);
            sk += __shfl_xor(sk, m);
        }
        if (lane == 0) {
            atomicAdd(&rparts[fi],            sq*sk);
            atomicAdd(&rparts[MAXFIX + fi],   sq*sq);
            atomicAdd(&rparts[2*MAXFIX + fi], sk*sk);
        }
        __syncthreads();    // protect x0/x1 before next token overwrites
    }
}

// repair, pass 2: overwrite cosv for flagged tokens with exact value
__global__ __launch_bounds__(128)
void repair_fin_kernel(const float* __restrict__ rparts,
                       const int* __restrict__ flags,
                       float* __restrict__ cosv)
{
    const int fi = threadIdx.x;
    const int count = min(flags[0], MAXFIX);
    if (fi < count) {
        const int t = flags[1 + fi];
        const float D = rparts[fi];
        const float Q = rparts[MAXFIX + fi];
        const float K = rparts[2*MAXFIX + fi];
        cosv[t] = D / (fmaxf(sqrtf(Q), 1e-12f) * fmaxf(sqrtf(K), 1e-12f));
    }
}

// ---------------------------------------------------------------------------
// EMA scan (round-1-verified structure)
// ---------------------------------------------------------------------------
__device__ inline void build_seg_masks(const float* __restrict__ cosv,
                                       int b, int l0, float* dec, int* msk)
{
    const int tid = threadIdx.x;
    if (tid < SEGLEN) {
        const int l = l0 + tid;
        float p;
        if (l == 0) {
            p = 1.f;
        } else {
            const float c = cosv[b*Lc + l - 1];
            p = (1.f - c) * 0.5f;
            p = fminf(fmaxf(p, 0.f), 1.f);
        }
        dec[tid] = 1.f - p;
        msk[tid] = (p > 0.5f) ? 1 : 0;
    }
    __syncthreads();
}

__global__ __launch_bounds__(256)
void seg_pass1_kernel(const float* __restrict__ X,
                      const float* __restrict__ cosv,
                      float* __restrict__ Aseg,
                      float* __restrict__ Bseg)
{
    __shared__ float dec[SEGLEN];
    __shared__ int   msk[SEGLEN];
    const int tid = threadIdx.x;
    const int b = blockIdx.x >> 6;
    const int s = blockIdx.x & 63;
    const int l0 = s * SEGLEN;
    build_seg_masks(cosv, b, l0, dec, msk);

    float4 st = make_float4(0.f, 0.f, 0.f, 0.f);
    float A = 1.f;
    const float* xb = X + (size_t)(b*Lc + l0)*Dc + tid*4;
    for (int i = 0; i < SEGLEN; i++) {
        if (msk[i]) {
            const float d = dec[i];
            const float w = 1.f - d;
            const float4 xv = *(const float4*)(xb + (size_t)i*Dc);
            st.x = d*st.x + w*xv.x;
            st.y = d*st.y + w*xv.y;
            st.z = d*st.z + w*xv.z;
            st.w = d*st.w + w*xv.w;
            A *= d;
        }
    }
    *(float4*)&Bseg[(size_t)blockIdx.x*Dc + tid*4] = st;
    if (tid == 0) Aseg[blockIdx.x] = A;
}

__global__ __launch_bounds__(256)
void seg_combine_kernel(const float* __restrict__ Aseg,
                        const float* __restrict__ Bseg,
                        const float* __restrict__ init_state,
                        float* __restrict__ carry)
{
    const int tid = threadIdx.x;
    const int b = blockIdx.x;
    float4 c = *(const float4*)&init_state[(size_t)b*Dc + tid*4];
    for (int s = 0; s < NSEG; s++) {
        const size_t idx = (size_t)(b*NSEG + s);
        *(float4*)&carry[idx*Dc + tid*4] = c;
        const float a = Aseg[idx];
        const float4 Bv = *(const float4*)&Bseg[idx*Dc + tid*4];
        c.x = a*c.x + Bv.x;
        c.y = a*c.y + Bv.y;
        c.z = a*c.z + Bv.z;
        c.w = a*c.w + Bv.w;
    }
}

__global__ __launch_bounds__(256)
void seg_pass2_kernel(const float* __restrict__ X,
                      const float* __restrict__ RES,
                      const float* __restrict__ cosv,
                      const float* __restrict__ carry,
                      float* __restrict__ OUT)
{
    __shared__ float dec[SEGLEN];
    __shared__ int   msk[SEGLEN];
    const int tid = threadIdx.x;
    const int b = blockIdx.x >> 6;
    const int s = blockIdx.x & 63;
    const int l0 = s * SEGLEN;
    build_seg_masks(cosv, b, l0, dec, msk);

    float4 st = *(const float4*)&carry[(size_t)blockIdx.x*Dc + tid*4];
    const size_t base = (size_t)(b*Lc + l0)*Dc + tid*4;
    const float* xb = X   + base;
    const float* rb = RES + base;
    float*       ob = OUT + base;
    for (int i = 0; i < SEGLEN; i++) {
        if (msk[i]) {
            const float d = dec[i];
            const float w = 1.f - d;
            const float4 xv = *(const float4*)(xb + (size_t)i*Dc);
            st.x = d*st.x + w*xv.x;
            st.y = d*st.y + w*xv.y;
            st.z = d*st.z + w*xv.z;
            st.w = d*st.w + w*xv.w;
        }
        const float4 rv = *(const float4*)(rb + (size_t)i*Dc);
        float4 ov;
        ov.x = rv.x + st.x;
        ov.y = rv.y + st.y;
        ov.z = rv.z + st.z;
        ov.w = rv.w + st.w;
        *(float4*)(ob + (size_t)i*Dc) = ov;
    }
}

// ---------------------------------------------------------------------------
extern "C" void kernel_launch(void* const* d_in, const int* in_sizes, int n_in,
                              void* d_out, int out_size, void* d_ws, size_t ws_size,
                              hipStream_t stream)
{
    const float* X    = (const float*)d_in[0];
    const float* RES  = (const float*)d_in[1];
    const float* QW   = (const float*)d_in[2];
    const float* KW   = (const float*)d_in[3];
    const float* INIT = (const float*)d_in[4];
    float* OUT = (float*)d_out;

    char* ws = (char*)d_ws;
    us*    Qhi   = (us*)   (ws + OFF_QHI);
    us*    Qlo   = (us*)   (ws + OFF_QLO);
    us*    Khi   = (us*)   (ws + OFF_KHI);
    us*    Klo   = (us*)   (ws + OFF_KLO);
    float* parts = (float*)(ws + OFF_PARTS);
    int*   flags = (int*)  (ws + OFF_FLAGS);
    float* rparts= (float*)(ws + OFF_RPART);
    float* cosv  = (float*)(ws + OFF_COSV);
    float* Aseg  = (float*)(ws + OFF_ASEG);
    float* Bseg  = (float*)(ws + OFF_BSEG);
    float* carry = (float*)(ws + OFF_CARRY);

    zero_kernel       <<<192,  256, 0, stream>>>(parts, flags, rparts);
    convert_w_kernel  <<<1024, 256, 0, stream>>>(QW, Qhi, Qlo);
    convert_w_kernel  <<<1024, 256, 0, stream>>>(KW, Khi, Klo);
    gemm_cos_kernel   <<<1024, 256, 0, stream>>>(X, Qhi, Qlo, Khi, Klo, parts);
    cos_fin_kernel    <<<64,   256, 0, stream>>>(parts, cosv, flags);
    repair_partial_kernel<<<256, 256, 0, stream>>>(X, QW, KW, flags, rparts);
    repair_fin_kernel <<<1,    128, 0, stream>>>(rparts, flags, cosv);
    seg_pass1_kernel  <<<Bc*NSEG, 256, 0, stream>>>(X, cosv, Aseg, Bseg);
    seg_combine_kernel<<<Bc,      256, 0, stream>>>(Aseg, Bseg, INIT, carry);
    seg_pass2_kernel  <<<Bc*NSEG, 256, 0, stream>>>(X, RES, cosv, carry, OUT);
}